// Round 1
// baseline (63270.142 us; speedup 1.0000x reference)
//
#include <hip/hip_runtime.h>
#include <hip/hip_cooperative_groups.h>
#include <math.h>

namespace cg = cooperative_groups;

#define T_SEQ 500
#define BATCH 200
#define DIN1  300
#define HID1  256
#define HID2  300
#define KTOT  556          // layer1: 300+256, layer2: 256+300 (both 556)
#define NT1   64           // 1024 gate rows / 16
#define NT2   75           // 1200 gate rows / 16
#define NBLK  (NT1*4 + NT2*4)   // 256 + 300 = 556 blocks
#define KC    48           // k-chunk width
#define NKC   12           // 12*48 = 576 >= 556 (zero-padded tail)
#define AST   50           // A_lds row stride (2-way bank pattern, 8B-aligned)
#define GST   66           // gate_lds row stride

// ws float offsets
#define WS_H1   0                       // [2][256*200]
#define WS_O1   102400                  // [2][256*200] masked layer1 outputs
#define WS_H2   204800                  // [2][300*200]
#define WS_C1   324800                  // [256*200]
#define WS_C2   376000                  // [300*200]
#define WS_TOT  436000                  // floats (~1.75 MB)

__device__ __forceinline__ float sigf(float v) {
    return 1.0f / (1.0f + __expf(-v));
}
__device__ __forceinline__ float tanh_fast(float v) {
    v = fminf(15.0f, fmaxf(-15.0f, v));
    float e = __expf(2.0f * v);
    return (e - 1.0f) / (e + 1.0f);
}

__global__ __launch_bounds__(256, 3)
void lstm_fused(const float* __restrict__ x, const int* __restrict__ lengths,
                const float* __restrict__ Wih1, const float* __restrict__ Whh1,
                const float* __restrict__ bih1, const float* __restrict__ bhh1,
                const float* __restrict__ Wih2, const float* __restrict__ Whh2,
                const float* __restrict__ bih2, const float* __restrict__ bhh2,
                float* __restrict__ out, float* __restrict__ ws,
                int it_begin, int it_end, int coop)
{
    __shared__ float W_lds[16*KTOT + 64];   // persistent weight tile (gate-interleaved rows)
    __shared__ float bias_lds[16];
    __shared__ float A_lds[64*AST];         // activation k-chunk
    __shared__ float gate_lds[16*GST];

    const int tid = threadIdx.x;
    const int blk = blockIdx.x;
    const bool l1 = (blk < NT1*4);
    const int lb  = l1 ? blk : blk - NT1*4;
    const int nt  = lb >> 2;   // n-tile (16 gate rows = 4 hidden units)
    const int mc  = lb & 3;    // m-chunk (64 batches)
    const int H   = l1 ? HID1 : HID2;
    const int DIN = l1 ? DIN1 : HID1;

    float* h1 = ws + WS_H1;
    float* o1 = ws + WS_O1;
    float* h2 = ws + WS_H2;
    float* c1 = ws + WS_C1;
    float* c2 = ws + WS_C2;

    // ---- stage weights once: row r = 4*h_local + gate, cols = [Wih | Whh] ----
    {
        const float* Wih = l1 ? Wih1 : Wih2;
        const float* Whh = l1 ? Whh1 : Whh2;
        for (int e = tid; e < 16*KTOT; e += 256) {
            int r = e / KTOT, k = e - r*KTOT;
            int hl = r >> 2, g = r & 3;
            int grow = g*H + nt*4 + hl;
            float v = (k < DIN) ? Wih[grow*DIN + k] : Whh[grow*H + (k - DIN)];
            W_lds[r*KTOT + k] = v;
        }
        for (int e = 16*KTOT + tid; e < 16*KTOT + 64; e += 256) W_lds[e] = 0.0f; // tail slack (avoid NaN*0)
        if (tid < 16) {
            int hl = tid >> 2, g = tid & 3;
            int grow = g*H + nt*4 + hl;
            bias_lds[tid] = l1 ? (bih1[grow] + bhh1[grow]) : (bih2[grow] + bhh2[grow]);
        }
    }

    // GEMM mapping: thread -> (bpos, gpos); batches {bpos, bpos+32}, rows {2g, 2g+1}
    const int bpos = tid & 31;
    const int gpos = tid >> 5;          // 0..7
    const int r0 = 2*gpos, r1 = 2*gpos + 1;

    // epilogue mapping: thread -> (hidden unit local, batch local)
    const int e_hl = tid >> 6;          // 0..3
    const int e_bl = tid & 63;
    const int e_bg = mc*64 + e_bl;
    const int unit = nt*4 + e_hl;
    int len_r = 0;
    if (l1 && e_bg < BATCH) len_r = lengths[e_bg];

    __syncthreads();

    for (int it = it_begin; it < it_end; ++it) {
        const bool active = l1 ? (it < T_SEQ) : (it >= 1);
        if (active) {
            const int t = l1 ? it : (it - 1);
            float acc00 = bias_lds[r0], acc01 = bias_lds[r0];
            float acc10 = bias_lds[r1], acc11 = bias_lds[r1];

            const float* hprev1 = h1 + (it & 1)*51200;          // layer1 reads h1[it&1]
            const float* src_a  = o1 + ((it - 1) & 1)*51200;    // layer2 input = o1[(it-1)&1]
            const float* src_b  = h2 + ((it - 1) & 1)*60000;    // layer2 state = h2[(it-1)&1]

            for (int kc = 0; kc < NKC; ++kc) {
                const int k0 = kc*KC;
                // ---- stage A chunk [64 b][48 k] ----
                if (l1) {
                    if (k0 < DIN1) {        // x part (coalesced along k)
                        const float* xr = x + (size_t)t*DIN1;
                        for (int e = tid; e < 64*KC; e += 256) {
                            int j = e % KC, bl = e / KC;
                            int k = k0 + j;
                            if (k < DIN1) {
                                int bg = mc*64 + bl;
                                float v = (bg < BATCH) ? xr[(size_t)bg*(T_SEQ*DIN1) + k] : 0.0f;
                                A_lds[bl*AST + j] = v;
                            }
                        }
                    }
                    if (k0 + KC > DIN1) {   // h1 part (coalesced along b)
                        for (int e = tid; e < 64*KC; e += 256) {
                            int bl = e & 63, j = e >> 6;
                            int k = k0 + j;
                            if (k >= DIN1) {
                                int bg = mc*64 + bl;
                                float v = (k < KTOT && bg < BATCH) ? hprev1[(k - DIN1)*BATCH + bg] : 0.0f;
                                A_lds[bl*AST + j] = v;
                            }
                        }
                    }
                } else {                    // layer2: both parts [unit][batch], coalesced along b
                    for (int e = tid; e < 64*KC; e += 256) {
                        int bl = e & 63, j = e >> 6;
                        int k = k0 + j;
                        int bg = mc*64 + bl;
                        float v = 0.0f;
                        if (bg < BATCH) {
                            if (k < HID1)      v = src_a[k*BATCH + bg];
                            else if (k < KTOT) v = src_b[(k - HID1)*BATCH + bg];
                        }
                        A_lds[bl*AST + j] = v;
                    }
                }
                __syncthreads();
                // ---- accumulate 2b x 2g over 48 k ----
                const float* Ar0 = &A_lds[bpos*AST];
                const float* Ar1 = &A_lds[(bpos+32)*AST];
                const float* Wr0 = &W_lds[r0*KTOT + k0];
                const float* Wr1 = &W_lds[r1*KTOT + k0];
                #pragma unroll
                for (int j = 0; j < KC; j += 4) {
                    float2 a0  = *(const float2*)(Ar0 + j);
                    float2 a0b = *(const float2*)(Ar0 + j + 2);
                    float2 a1  = *(const float2*)(Ar1 + j);
                    float2 a1b = *(const float2*)(Ar1 + j + 2);
                    float4 w0  = *(const float4*)(Wr0 + j);
                    float4 w1  = *(const float4*)(Wr1 + j);
                    acc00 = fmaf(a0.x,  w0.x, acc00);
                    acc00 = fmaf(a0.y,  w0.y, acc00);
                    acc00 = fmaf(a0b.x, w0.z, acc00);
                    acc00 = fmaf(a0b.y, w0.w, acc00);
                    acc01 = fmaf(a1.x,  w0.x, acc01);
                    acc01 = fmaf(a1.y,  w0.y, acc01);
                    acc01 = fmaf(a1b.x, w0.z, acc01);
                    acc01 = fmaf(a1b.y, w0.w, acc01);
                    acc10 = fmaf(a0.x,  w1.x, acc10);
                    acc10 = fmaf(a0.y,  w1.y, acc10);
                    acc10 = fmaf(a0b.x, w1.z, acc10);
                    acc10 = fmaf(a0b.y, w1.w, acc10);
                    acc11 = fmaf(a1.x,  w1.x, acc11);
                    acc11 = fmaf(a1.y,  w1.y, acc11);
                    acc11 = fmaf(a1b.x, w1.z, acc11);
                    acc11 = fmaf(a1b.y, w1.w, acc11);
                }
                __syncthreads();
            }
            // ---- gates -> LDS for per-unit gather ----
            gate_lds[r0*GST + bpos]      = acc00;
            gate_lds[r0*GST + bpos + 32] = acc01;
            gate_lds[r1*GST + bpos]      = acc10;
            gate_lds[r1*GST + bpos + 32] = acc11;
            __syncthreads();
            // ---- elementwise LSTM cell update ----
            if (e_bg < BATCH) {
                float gi = gate_lds[(4*e_hl + 0)*GST + e_bl];
                float gf = gate_lds[(4*e_hl + 1)*GST + e_bl];
                float gc = gate_lds[(4*e_hl + 2)*GST + e_bl];
                float go = gate_lds[(4*e_hl + 3)*GST + e_bl];
                float iv = sigf(gi), fv = sigf(gf), cv = tanh_fast(gc), ov = sigf(go);
                if (l1) {
                    float cprev = c1[unit*BATCH + e_bg];
                    float c = fmaf(fv, cprev, iv*cv);
                    c1[unit*BATCH + e_bg] = c;
                    float h = ov * tanh_fast(c);
                    h1[((it + 1) & 1)*51200 + unit*BATCH + e_bg] = h;
                    o1[(it & 1)*51200 + unit*BATCH + e_bg] = (it < len_r) ? h : 0.0f;  // pad_packed mask
                    if (it == len_r - 1)
                        out[30000000 + e_bg*HID1 + unit] = h;                           // h_value
                } else {
                    float cprev = c2[unit*BATCH + e_bg];
                    float c = fmaf(fv, cprev, iv*cv);
                    c2[unit*BATCH + e_bg] = c;
                    float h = ov * tanh_fast(c);
                    h2[(it & 1)*60000 + unit*BATCH + e_bg] = h;
                    out[(size_t)e_bg*150000 + (size_t)t*HID2 + unit] = h;               // out2[b,t,:]
                }
            }
        }
        if (coop) cg::this_grid().sync();
    }
}

extern "C" void kernel_launch(void* const* d_in, const int* in_sizes, int n_in,
                              void* d_out, int out_size, void* d_ws, size_t ws_size,
                              hipStream_t stream) {
    const float* x     = (const float*)d_in[0];
    const int*   lens  = (const int*)  d_in[1];
    const float* Wih1  = (const float*)d_in[2];
    const float* Whh1  = (const float*)d_in[3];
    const float* bih1  = (const float*)d_in[4];
    const float* bhh1  = (const float*)d_in[5];
    const float* Wih2  = (const float*)d_in[6];
    const float* Whh2  = (const float*)d_in[7];
    const float* bih2  = (const float*)d_in[8];
    const float* bhh2  = (const float*)d_in[9];
    float* out = (float*)d_out;
    float* ws  = (float*)d_ws;

    // zero h1[0], h2[0], c1, c2 (and harmless rest) every call — deterministic
    hipMemsetAsync(d_ws, 0, (size_t)WS_TOT * sizeof(float), stream);

    int ib = 0, ie = T_SEQ + 1, coop = 1;
    void* args[] = {(void*)&x, (void*)&lens, (void*)&Wih1, (void*)&Whh1, (void*)&bih1, (void*)&bhh1,
                    (void*)&Wih2, (void*)&Whh2, (void*)&bih2, (void*)&bhh2,
                    (void*)&out, (void*)&ws, (void*)&ib, (void*)&ie, (void*)&coop};
    hipError_t err = hipLaunchCooperativeKernel((const void*)lstm_fused, dim3(NBLK), dim3(256),
                                                args, 0, stream);
    if (err != hipSuccess) {
        (void)hipGetLastError();  // clear, fall back to per-step launches (state fully in ws)
        for (int it = 0; it <= T_SEQ; ++it) {
            hipLaunchKernelGGL(lstm_fused, dim3(NBLK), dim3(256), 0, stream,
                               x, lens, Wih1, Whh1, bih1, bhh1, Wih2, Whh2, bih2, bhh2,
                               out, ws, it, it + 1, 0);
        }
    }
}

// Round 2
// 31613.467 us; speedup vs baseline: 2.0014x; 2.0014x over previous
//
#include <hip/hip_runtime.h>
#include <hip/hip_cooperative_groups.h>
#include <math.h>

namespace cg = cooperative_groups;

#define TSEQ 500
#define BQ   200
#define DIN  300
#define H1   256
#define H2   300
#define K1   556          // 300+256 == 256+300
#define KP   576          // K padded: 18 MFMA k-steps of 32
#define KCH  72           // 576/8 chunks of 8 bf16 (16B)
#define H1P  264          // h1/o1 row stride (units, padded, 16B-aligned rows)
#define H2P  304          // h2 row stride
#define BP   224          // batch padded to 7*32
#define NBLK 490          // 7 batch-chunks * (32 L1 + 38 L2 gate-tiles)

// ws byte offsets (all 16B aligned)
#define WS_H1  0          // ushort [2][BP][H1P]
#define WS_O1  236544     // ushort [2][BP][H1P]  masked layer1 out
#define WS_H2  473088     // ushort [2][BP][H2P]
#define WS_C1  745472     // float  [256][BP]
#define WS_C2  974848     // float  [304][BP]
#define WS_END 1247232
#define H1HALF (BP*H1P)   // 59136 ushorts per buffer half
#define H2HALF (BP*H2P)   // 68096

typedef __attribute__((ext_vector_type(8))) short short8;
typedef __attribute__((ext_vector_type(4))) float f32x4;

__device__ __forceinline__ float sigf(float v){ return 1.0f/(1.0f+__expf(-v)); }
__device__ __forceinline__ float tanhf_(float v){
    v = fminf(15.0f, fmaxf(-15.0f, v));
    float e = __expf(2.0f*v);
    return (e-1.0f)/(e+1.0f);
}
__device__ __forceinline__ unsigned short f2bf(float f){   // RNE, finite inputs
    unsigned int xx = __builtin_bit_cast(unsigned int, f);
    xx = (xx + 0x7FFFu + ((xx>>16)&1u)) >> 16;
    return (unsigned short)xx;
}

__global__ __launch_bounds__(256, 2)
void lstm_mfma(const float* __restrict__ x, const int* __restrict__ lengths,
               const float* __restrict__ Wih1, const float* __restrict__ Whh1,
               const float* __restrict__ bih1, const float* __restrict__ bhh1,
               const float* __restrict__ Wih2, const float* __restrict__ Whh2,
               const float* __restrict__ bih2, const float* __restrict__ bhh2,
               float* __restrict__ out, char* __restrict__ wsb,
               int it_begin, int it_end, int coop)
{
    // LDS: 36864 + 36864 + 4224 + 128 + 544 + 544 + 1056 = 80224 B -> 2 blocks/CU
    __shared__ unsigned short Wl[32*KP];     // weights, swizzled [row][k] bf16 (persistent)
    __shared__ unsigned short Al[32*KP];     // activations, swizzled [batch][k] bf16
    __shared__ float gl[32*33];              // gate exchange (stride 33)
    __shared__ float bias[32];
    __shared__ unsigned short htr[8*34];     // h transpose buffer (bf16)
    __shared__ unsigned short otr[8*34];     // masked-h transpose buffer (L1)
    __shared__ float ftr[8*33];              // out2 f32 transpose buffer (L2)

    const int tid = threadIdx.x;
    const int bid = blockIdx.x;
    const int mc = bid/70;                   // batch chunk 0..6
    const int local = bid - mc*70;
    const bool l1 = local < 32;
    const int gt = l1 ? local : local - 32;  // gate tile (8 hidden units)
    const int Hl   = l1 ? H1 : H2;
    const int DINl = l1 ? DIN : H1;

    unsigned short* h1s = (unsigned short*)(wsb + WS_H1);
    unsigned short* o1s = (unsigned short*)(wsb + WS_O1);
    unsigned short* h2s = (unsigned short*)(wsb + WS_H2);
    float* c1 = (float*)(wsb + WS_C1);
    float* c2 = (float*)(wsb + WS_C2);

    // ---- stage weights once: row r = 4*u_local + gate, swizzled 16B chunks ----
    {
        const float* Wih = l1 ? Wih1 : Wih2;
        const float* Whh = l1 ? Whh1 : Whh2;
        for (int i = 0; i < 9; ++i){
            int e = tid + i*256;             // 32*72 = 2304 chunks
            int r = e/KCH, kc = e - r*KCH;
            int u = r>>2, g = r&3;
            int unit = gt*8 + u;
            bool vr = unit < Hl;             // L2 tile 37: units 300..303 are pad
            int grow = g*Hl + unit;
            unsigned short v8[8];
            #pragma unroll
            for (int j = 0; j < 8; ++j){
                int k = kc*8 + j;
                float v = 0.0f;
                if (vr && k < K1)
                    v = (k < DINl) ? Wih[(size_t)grow*DINl + k]
                                   : Whh[(size_t)grow*Hl + (k - DINl)];
                v8[j] = f2bf(v);
            }
            *(short8*)&Wl[r*KP + ((kc ^ (r&7))<<3)] = *(short8*)v8;
        }
        if (tid < 32){
            int u = tid>>2, g = tid&3, unit = gt*8 + u;
            bias[tid] = (unit < Hl)
                ? ((l1?bih1:bih2)[g*Hl+unit] + (l1?bhh1:bhh2)[g*Hl+unit]) : 0.0f;
        }
    }

    // MFMA lane mapping: A-frag row = lane&15, k-group = lane>>4; D: row=(l>>4)*4+q, col=l&15
    const int wave = tid>>6, lane = tid&63;
    const int wr = wave>>1, wb = wave&1;     // fragment grid 2x2 of 16x16
    const int fr = lane&15, fg = lane>>4;
    const int sw = fr&7;                     // (wr*16+fr)&7 == fr&7 (wr*16 mult of 8)
    const unsigned short* wrow = &Wl[(wr*16 + fr)*KP];
    const unsigned short* arow = &Al[(wb*16 + fr)*KP];
    const int gm = wr*16 + fg*4, gn = wb*16 + fr;

    // epilogue mapping: (hidden unit local, batch local)
    const int eu = tid>>5, ebl = tid&31;
    const int bg_e = mc*32 + ebl;
    const int unit_e = gt*8 + eu;
    const int len_r = (l1 && bg_e < BQ) ? lengths[bg_e] : -1;

    __syncthreads();

    for (int it = it_begin; it < it_end; ++it){
        const bool active = l1 ? (it < TSEQ) : (it >= 1);
        if (active){
            const int t = l1 ? it : it - 1;
            const unsigned short* h1p = h1s + (it&1)*H1HALF;
            const unsigned short* o1p = o1s + ((it-1)&1)*H1HALF;
            const unsigned short* h2p = h2s + ((it-1)&1)*H2HALF;

            // ---- stage full activation panel [32 b][576 k] (bf16, swizzled) ----
            for (int i = 0; i < 9; ++i){
                int e = tid + i*256;
                int bl = e/KCH, kc = e - bl*KCH;
                int bg = mc*32 + bl;
                unsigned short v8[8];
                if (bg >= BQ || kc >= 70){
                    #pragma unroll
                    for (int j = 0; j < 8; ++j) v8[j] = 0;
                } else if (l1){
                    if (kc <= 36){                       // pure x: fp32 -> bf16
                        const float* xp = x + ((size_t)bg*TSEQ + t)*DIN + kc*8;
                        float4 f0 = *(const float4*)xp;
                        float4 f1 = *(const float4*)(xp + 4);
                        v8[0]=f2bf(f0.x); v8[1]=f2bf(f0.y); v8[2]=f2bf(f0.z); v8[3]=f2bf(f0.w);
                        v8[4]=f2bf(f1.x); v8[5]=f2bf(f1.y); v8[6]=f2bf(f1.z); v8[7]=f2bf(f1.w);
                    } else if (kc == 37){                // x/h boundary (k 296..303)
                        const float* xp = x + ((size_t)bg*TSEQ + t)*DIN;
                        #pragma unroll
                        for (int j = 0; j < 8; ++j){
                            int k = 296 + j;
                            v8[j] = (k < DIN) ? f2bf(xp[k]) : h1p[bg*H1P + (k-DIN)];
                        }
                    } else {                             // pure h1 (8B-aligned only)
                        const unsigned short* hp = h1p + bg*H1P + (kc*8 - DIN);
                        *(uint2*)&v8[0] = *(const uint2*)hp;
                        *(uint2*)&v8[4] = *(const uint2*)(hp + 4);
                    }
                } else {                                 // L2: o1 | h2, both 16B aligned
                    const unsigned short* sp = (kc <= 31)
                        ? (o1p + bg*H1P + kc*8)
                        : (h2p + bg*H2P + (kc*8 - 256)); // kc=69 reads pad zeros (kept 0)
                    *(short8*)v8 = *(const short8*)sp;
                }
                *(short8*)&Al[bl*KP + ((kc ^ (bl&7))<<3)] = *(short8*)v8;
            }
            __syncthreads();

            // ---- gates[32r x 32b] = W * A^T via 18 barrier-free MFMA steps ----
            f32x4 acc = {0.f, 0.f, 0.f, 0.f};
            #pragma unroll
            for (int ks = 0; ks < 18; ++ks){
                int off = ((ks*4 + fg) ^ sw) << 3;
                short8 wa = *(const short8*)(wrow + off);
                short8 ab = *(const short8*)(arow + off);
                acc = __builtin_amdgcn_mfma_f32_16x16x32_bf16(wa, ab, acc, 0, 0, 0);
            }
            #pragma unroll
            for (int q = 0; q < 4; ++q) gl[(gm+q)*33 + gn] = acc[q];
            __syncthreads();

            // ---- fp32 cell update ----
            {
                float gi = gl[(eu*4+0)*33 + ebl] + bias[eu*4+0];
                float gf = gl[(eu*4+1)*33 + ebl] + bias[eu*4+1];
                float gg = gl[(eu*4+2)*33 + ebl] + bias[eu*4+2];
                float go = gl[(eu*4+3)*33 + ebl] + bias[eu*4+3];
                float iv = sigf(gi), fv = sigf(gf), cv = tanhf_(gg), ov = sigf(go);
                if (l1){
                    float cp = c1[unit_e*BP + bg_e];
                    float c  = fmaf(fv, cp, iv*cv);
                    c1[unit_e*BP + bg_e] = c;
                    float h  = ov * tanhf_(c);
                    float hm = (it < len_r) ? h : 0.0f;   // pad_packed mask
                    htr[eu*34 + ebl] = f2bf(h);
                    otr[eu*34 + ebl] = f2bf(hm);
                    if (it == len_r - 1)
                        out[30000000 + (size_t)bg_e*H1 + unit_e] = h;  // h_value (fp32 h)
                } else {
                    float cp = c2[unit_e*BP + bg_e];
                    float c  = fmaf(fv, cp, iv*cv);
                    c2[unit_e*BP + bg_e] = c;
                    float h  = ov * tanhf_(c);
                    htr[eu*34 + ebl] = (unit_e < H2) ? f2bf(h) : (unsigned short)0;
                    ftr[eu*33 + ebl] = h;
                }
            }
            __syncthreads();

            // ---- packed transposed stores: 32 threads, 16B per batch row ----
            if (tid < 32){
                int bgp = mc*32 + tid;
                unsigned short p8[8];
                if (l1){
                    #pragma unroll
                    for (int u2 = 0; u2 < 8; ++u2) p8[u2] = htr[u2*34 + tid];
                    *(short8*)&h1s[((it+1)&1)*H1HALF + bgp*H1P + gt*8] = *(short8*)p8;
                    #pragma unroll
                    for (int u2 = 0; u2 < 8; ++u2) p8[u2] = otr[u2*34 + tid];
                    *(short8*)&o1s[(it&1)*H1HALF + bgp*H1P + gt*8] = *(short8*)p8;
                } else {
                    #pragma unroll
                    for (int u2 = 0; u2 < 8; ++u2) p8[u2] = htr[u2*34 + tid];
                    *(short8*)&h2s[(it&1)*H2HALF + bgp*H2P + gt*8] = *(short8*)p8;
                    if (bgp < BQ){
                        float* op = out + (size_t)bgp*150000 + (size_t)t*300 + gt*8;
                        float4 q0;
                        q0.x = ftr[0*33+tid]; q0.y = ftr[1*33+tid];
                        q0.z = ftr[2*33+tid]; q0.w = ftr[3*33+tid];
                        *(float4*)op = q0;
                        if (gt < 37){   // tile 37 covers units 296..303: only 296..299 valid
                            float4 q1;
                            q1.x = ftr[4*33+tid]; q1.y = ftr[5*33+tid];
                            q1.z = ftr[6*33+tid]; q1.w = ftr[7*33+tid];
                            *(float4*)(op + 4) = q1;
                        }
                    }
                }
            }
        }
        if (coop) cg::this_grid().sync();
    }
}

extern "C" void kernel_launch(void* const* d_in, const int* in_sizes, int n_in,
                              void* d_out, int out_size, void* d_ws, size_t ws_size,
                              hipStream_t stream) {
    const float* x    = (const float*)d_in[0];
    const int*   lens = (const int*)  d_in[1];
    const float* Wih1 = (const float*)d_in[2];
    const float* Whh1 = (const float*)d_in[3];
    const float* bih1 = (const float*)d_in[4];
    const float* bhh1 = (const float*)d_in[5];
    const float* Wih2 = (const float*)d_in[6];
    const float* Whh2 = (const float*)d_in[7];
    const float* bih2 = (const float*)d_in[8];
    const float* bhh2 = (const float*)d_in[9];
    float* out = (float*)d_out;
    char*  ws  = (char*)d_ws;

    // zero state buffers (h/o/h2 init + c init + pad regions) every call
    hipMemsetAsync(d_ws, 0, (size_t)WS_END, stream);

    int ib = 0, ie = TSEQ + 1, coop = 1;
    void* args[] = {(void*)&x, (void*)&lens, (void*)&Wih1, (void*)&Whh1, (void*)&bih1, (void*)&bhh1,
                    (void*)&Wih2, (void*)&Whh2, (void*)&bih2, (void*)&bhh2,
                    (void*)&out, (void*)&ws, (void*)&ib, (void*)&ie, (void*)&coop};
    hipError_t err = hipLaunchCooperativeKernel((const void*)lstm_mfma, dim3(NBLK), dim3(256),
                                                args, 0, stream);
    if (err != hipSuccess) {
        (void)hipGetLastError();   // fall back: one launch per iteration (state in ws)
        for (int it = 0; it <= TSEQ; ++it) {
            hipLaunchKernelGGL(lstm_mfma, dim3(NBLK), dim3(256), 0, stream,
                               x, lens, Wih1, Whh1, bih1, bhh1, Wih2, Whh2, bih2, bhh2,
                               out, ws, it, it + 1, 0);
        }
    }
}

// Round 3
// 16717.162 us; speedup vs baseline: 3.7847x; 1.8911x over previous
//
#include <hip/hip_runtime.h>
#include <math.h>

#define TSEQ 500
#define BQ   200
#define DIN  300
#define H1   256
#define H2   300
#define K1   556          // 300+256 == 256+300
#define KP   576          // K padded: 18 MFMA k-steps of 32
#define KCH  72           // 576/8 chunks of 8 bf16 (16B)
#define H1P  264          // h1/o1 row stride (units, padded, 16B-aligned rows)
#define H2P  304          // h2 row stride
#define BP   224          // batch padded to 7*32
#define NBLK 490          // 7 batch-chunks * (32 L1 + 38 L2 gate-tiles)
#define CBLK 70           // blocks per chunk

// ws byte offsets (all 16B aligned)
#define WS_H1  0          // ushort [2][BP][H1P]
#define WS_O1  236544     // ushort [2][BP][H1P]  masked layer1 out
#define WS_H2  473088     // ushort [2][BP][H2P]
#define WS_C1  745472     // float  [256][BP]
#define WS_C2  974848     // float  [304][BP]
#define WS_BAR 1247232    // 7 chunk barriers: cnt at c*256, gen at c*256+128
#define WS_MSET 1249024
#define H1HALF (BP*H1P)   // 59136 ushorts per buffer half
#define H2HALF (BP*H2P)   // 68096

typedef __attribute__((ext_vector_type(8))) short short8;
typedef __attribute__((ext_vector_type(4))) float f32x4;

__device__ __forceinline__ float sigf(float v){ return 1.0f/(1.0f+__expf(-v)); }
__device__ __forceinline__ float tanhf_(float v){
    v = fminf(15.0f, fmaxf(-15.0f, v));
    float e = __expf(2.0f*v);
    return (e-1.0f)/(e+1.0f);
}
__device__ __forceinline__ unsigned short f2bf(float f){   // RNE, finite inputs
    unsigned int xx = __builtin_bit_cast(unsigned int, f);
    xx = (xx + 0x7FFFu + ((xx>>16)&1u)) >> 16;
    return (unsigned short)xx;
}

__global__ __launch_bounds__(256, 2)
void lstm_mfma(const float* __restrict__ x, const int* __restrict__ lengths,
               const float* __restrict__ Wih1, const float* __restrict__ Whh1,
               const float* __restrict__ bih1, const float* __restrict__ bhh1,
               const float* __restrict__ Wih2, const float* __restrict__ Whh2,
               const float* __restrict__ bih2, const float* __restrict__ bhh2,
               float* __restrict__ out, char* __restrict__ wsb,
               int it_begin, int it_end, int coop)
{
    __shared__ unsigned short Wl[32*KP];     // weights, swizzled [row][k] bf16 (persistent)
    __shared__ unsigned short Al[32*KP];     // activations, swizzled [batch][k] bf16
    __shared__ float gl[32*33];              // gate exchange (stride 33)
    __shared__ float bias[32];
    __shared__ unsigned short htr[8*34];     // h transpose buffer (bf16)
    __shared__ unsigned short otr[8*34];     // masked-h transpose buffer (L1)
    __shared__ float ftr[8*33];              // out2 f32 transpose buffer (L2)

    const int tid = threadIdx.x;
    const int bid = blockIdx.x;
    const int mc = bid/70;                   // batch chunk 0..6
    const int local = bid - mc*70;
    const bool l1 = local < 32;
    const int gt = l1 ? local : local - 32;  // gate tile (8 hidden units)
    const int Hl   = l1 ? H1 : H2;
    const int DINl = l1 ? DIN : H1;

    unsigned short* h1s = (unsigned short*)(wsb + WS_H1);
    unsigned short* o1s = (unsigned short*)(wsb + WS_O1);
    unsigned short* h2s = (unsigned short*)(wsb + WS_H2);
    float* c1 = (float*)(wsb + WS_C1);
    float* c2 = (float*)(wsb + WS_C2);
    unsigned* barc = (unsigned*)(wsb + WS_BAR + mc*256);        // arrive counter
    unsigned* barg = (unsigned*)(wsb + WS_BAR + mc*256 + 128);  // release generation

    // ---- stage weights once: row r = 4*u_local + gate, swizzled 16B chunks ----
    {
        const float* Wih = l1 ? Wih1 : Wih2;
        const float* Whh = l1 ? Whh1 : Whh2;
        for (int i = 0; i < 9; ++i){
            int e = tid + i*256;             // 32*72 = 2304 chunks
            int r = e/KCH, kc = e - r*KCH;
            int u = r>>2, g = r&3;
            int unit = gt*8 + u;
            bool vr = unit < Hl;             // L2 tile 37: units 300..303 are pad
            int grow = g*Hl + unit;
            unsigned short v8[8];
            #pragma unroll
            for (int j = 0; j < 8; ++j){
                int k = kc*8 + j;
                float v = 0.0f;
                if (vr && k < K1)
                    v = (k < DINl) ? Wih[(size_t)grow*DINl + k]
                                   : Whh[(size_t)grow*Hl + (k - DINl)];
                v8[j] = f2bf(v);
            }
            *(short8*)&Wl[r*KP + ((kc ^ (r&7))<<3)] = *(short8*)v8;
        }
        if (tid < 32){
            int u = tid>>2, g = tid&3, unit = gt*8 + u;
            bias[tid] = (unit < Hl)
                ? ((l1?bih1:bih2)[g*Hl+unit] + (l1?bhh1:bhh2)[g*Hl+unit]) : 0.0f;
        }
    }

    // MFMA lane mapping: A-frag row = lane&15, k-group = lane>>4; D: row=(l>>4)*4+q, col=l&15
    const int wave = tid>>6, lane = tid&63;
    const int wr = wave>>1, wb = wave&1;     // fragment grid 2x2 of 16x16
    const int fr = lane&15, fg = lane>>4;
    const int sw = fr&7;                     // (wr*16+fr)&7 == fr&7 (wr*16 mult of 8)
    const unsigned short* wrow = &Wl[(wr*16 + fr)*KP];
    const unsigned short* arow = &Al[(wb*16 + fr)*KP];
    const int gm = wr*16 + fg*4, gn = wb*16 + fr;

    // epilogue mapping: (hidden unit local, batch local)
    const int eu = tid>>5, ebl = tid&31;
    const int bg_e = mc*32 + ebl;
    const int unit_e = gt*8 + eu;
    const int len_r = (l1 && bg_e < BQ) ? lengths[bg_e] : -1;

    __syncthreads();

    for (int it = it_begin; it < it_end; ++it){
        const bool active = l1 ? (it < TSEQ) : (it >= 1);
        if (active){
            const int t = l1 ? it : it - 1;
            const unsigned short* h1p = h1s + (it&1)*H1HALF;
            const unsigned short* o1p = o1s + ((it-1)&1)*H1HALF;
            const unsigned short* h2p = h2s + ((it-1)&1)*H2HALF;

            // ---- stage full activation panel [32 b][576 k] (bf16, swizzled) ----
            for (int i = 0; i < 9; ++i){
                int e = tid + i*256;
                int bl = e/KCH, kc = e - bl*KCH;
                int bg = mc*32 + bl;
                unsigned short v8[8];
                if (bg >= BQ || kc >= 70){
                    #pragma unroll
                    for (int j = 0; j < 8; ++j) v8[j] = 0;
                } else if (l1){
                    if (kc <= 36){                       // pure x: fp32 -> bf16
                        const float* xp = x + ((size_t)bg*TSEQ + t)*DIN + kc*8;
                        float4 f0 = *(const float4*)xp;
                        float4 f1 = *(const float4*)(xp + 4);
                        v8[0]=f2bf(f0.x); v8[1]=f2bf(f0.y); v8[2]=f2bf(f0.z); v8[3]=f2bf(f0.w);
                        v8[4]=f2bf(f1.x); v8[5]=f2bf(f1.y); v8[6]=f2bf(f1.z); v8[7]=f2bf(f1.w);
                    } else if (kc == 37){                // x/h boundary (k 296..303)
                        const float* xp = x + ((size_t)bg*TSEQ + t)*DIN;
                        #pragma unroll
                        for (int j = 0; j < 8; ++j){
                            int k = 296 + j;
                            v8[j] = (k < DIN) ? f2bf(xp[k]) : h1p[bg*H1P + (k-DIN)];
                        }
                    } else {                             // pure h1 (8B-aligned only)
                        const unsigned short* hp = h1p + bg*H1P + (kc*8 - DIN);
                        *(uint2*)&v8[0] = *(const uint2*)hp;
                        *(uint2*)&v8[4] = *(const uint2*)(hp + 4);
                    }
                } else {                                 // L2: o1 | h2, both 16B aligned
                    const unsigned short* sp = (kc <= 31)
                        ? (o1p + bg*H1P + kc*8)
                        : (h2p + bg*H2P + (kc*8 - 256)); // kc=69 reads pad zeros (kept 0)
                    *(short8*)v8 = *(const short8*)sp;
                }
                *(short8*)&Al[bl*KP + ((kc ^ (bl&7))<<3)] = *(short8*)v8;
            }
            __syncthreads();

            // ---- gates[32r x 32b] = W * A^T via 18 barrier-free MFMA steps ----
            f32x4 acc = {0.f, 0.f, 0.f, 0.f};
            #pragma unroll
            for (int ks = 0; ks < 18; ++ks){
                int off = ((ks*4 + fg) ^ sw) << 3;
                short8 wa = *(const short8*)(wrow + off);
                short8 ab = *(const short8*)(arow + off);
                acc = __builtin_amdgcn_mfma_f32_16x16x32_bf16(wa, ab, acc, 0, 0, 0);
            }
            #pragma unroll
            for (int q = 0; q < 4; ++q) gl[(gm+q)*33 + gn] = acc[q];
            __syncthreads();

            // ---- fp32 cell update ----
            {
                float gi = gl[(eu*4+0)*33 + ebl] + bias[eu*4+0];
                float gf = gl[(eu*4+1)*33 + ebl] + bias[eu*4+1];
                float gg = gl[(eu*4+2)*33 + ebl] + bias[eu*4+2];
                float go = gl[(eu*4+3)*33 + ebl] + bias[eu*4+3];
                float iv = sigf(gi), fv = sigf(gf), cv = tanhf_(gg), ov = sigf(go);
                if (l1){
                    float cp = c1[unit_e*BP + bg_e];
                    float c  = fmaf(fv, cp, iv*cv);
                    c1[unit_e*BP + bg_e] = c;
                    float h  = ov * tanhf_(c);
                    float hm = (it < len_r) ? h : 0.0f;   // pad_packed mask
                    htr[eu*34 + ebl] = f2bf(h);
                    otr[eu*34 + ebl] = f2bf(hm);
                    if (it == len_r - 1)
                        out[30000000 + (size_t)bg_e*H1 + unit_e] = h;  // h_value (fp32 h)
                } else {
                    float cp = c2[unit_e*BP + bg_e];
                    float c  = fmaf(fv, cp, iv*cv);
                    c2[unit_e*BP + bg_e] = c;
                    float h  = ov * tanhf_(c);
                    htr[eu*34 + ebl] = (unit_e < H2) ? f2bf(h) : (unsigned short)0;
                    ftr[eu*33 + ebl] = h;
                }
            }
            __syncthreads();

            // ---- packed transposed stores: 32 threads, 16B per batch row ----
            if (tid < 32){
                int bgp = mc*32 + tid;
                unsigned short p8[8];
                if (l1){
                    #pragma unroll
                    for (int u2 = 0; u2 < 8; ++u2) p8[u2] = htr[u2*34 + tid];
                    *(short8*)&h1s[((it+1)&1)*H1HALF + bgp*H1P + gt*8] = *(short8*)p8;
                    #pragma unroll
                    for (int u2 = 0; u2 < 8; ++u2) p8[u2] = otr[u2*34 + tid];
                    *(short8*)&o1s[(it&1)*H1HALF + bgp*H1P + gt*8] = *(short8*)p8;
                } else {
                    #pragma unroll
                    for (int u2 = 0; u2 < 8; ++u2) p8[u2] = htr[u2*34 + tid];
                    *(short8*)&h2s[(it&1)*H2HALF + bgp*H2P + gt*8] = *(short8*)p8;
                    if (bgp < BQ){
                        float* op = out + (size_t)bgp*150000 + (size_t)t*300 + gt*8;
                        float4 q0;
                        q0.x = ftr[0*33+tid]; q0.y = ftr[1*33+tid];
                        q0.z = ftr[2*33+tid]; q0.w = ftr[3*33+tid];
                        *(float4*)op = q0;
                        if (gt < 37){   // tile 37 covers units 296..303: only 296..299 valid
                            float4 q1;
                            q1.x = ftr[4*33+tid]; q1.y = ftr[5*33+tid];
                            q1.z = ftr[6*33+tid]; q1.w = ftr[7*33+tid];
                            *(float4*)(op + 4) = q1;
                        }
                    }
                }
            }
        }

        // ---- per-chunk decentralized barrier (replaces grid.sync) ----
        if (coop && (it + 1 < it_end)){
            __syncthreads();   // all block stores issued & waited (vmcnt drained -> in L2)
            if (tid == 0){
                __threadfence();   // agent release: write back local XCD L2 (whole-L2 op)
                unsigned old = __hip_atomic_fetch_add(barc, 1u, __ATOMIC_RELAXED,
                                                      __HIP_MEMORY_SCOPE_AGENT);
                if (old == (unsigned)(CBLK - 1)){
                    __hip_atomic_store(barc, 0u, __ATOMIC_RELAXED, __HIP_MEMORY_SCOPE_AGENT);
                    __hip_atomic_fetch_add(barg, 1u, __ATOMIC_RELAXED, __HIP_MEMORY_SCOPE_AGENT);
                } else {
                    const unsigned target = (unsigned)(it - it_begin + 1);
                    while (__hip_atomic_load(barg, __ATOMIC_RELAXED,
                                             __HIP_MEMORY_SCOPE_AGENT) < target)
                        __builtin_amdgcn_s_sleep(2);
                }
                __threadfence();   // agent acquire: invalidate stale local L2 lines
            }
            __syncthreads();
        }
    }
}

extern "C" void kernel_launch(void* const* d_in, const int* in_sizes, int n_in,
                              void* d_out, int out_size, void* d_ws, size_t ws_size,
                              hipStream_t stream) {
    const float* x    = (const float*)d_in[0];
    const int*   lens = (const int*)  d_in[1];
    const float* Wih1 = (const float*)d_in[2];
    const float* Whh1 = (const float*)d_in[3];
    const float* bih1 = (const float*)d_in[4];
    const float* bhh1 = (const float*)d_in[5];
    const float* Wih2 = (const float*)d_in[6];
    const float* Whh2 = (const float*)d_in[7];
    const float* bih2 = (const float*)d_in[8];
    const float* bhh2 = (const float*)d_in[9];
    float* out = (float*)d_out;
    char*  ws  = (char*)d_ws;

    // zero state buffers + pad regions + barrier counters every call (deterministic)
    hipMemsetAsync(d_ws, 0, (size_t)WS_MSET, stream);

    int ib = 0, ie = TSEQ + 1, coop = 1;
    void* args[] = {(void*)&x, (void*)&lens, (void*)&Wih1, (void*)&Whh1, (void*)&bih1, (void*)&bhh1,
                    (void*)&Wih2, (void*)&Whh2, (void*)&bih2, (void*)&bhh2,
                    (void*)&out, (void*)&ws, (void*)&ib, (void*)&ie, (void*)&coop};
    hipError_t err = hipLaunchCooperativeKernel((const void*)lstm_mfma, dim3(NBLK), dim3(256),
                                                args, 0, stream);
    if (err != hipSuccess) {
        (void)hipGetLastError();   // fall back: one launch per iteration (state in ws)
        for (int it = 0; it <= TSEQ; ++it) {
            hipLaunchKernelGGL(lstm_mfma, dim3(NBLK), dim3(256), 0, stream,
                               x, lens, Wih1, Whh1, bih1, bhh1, Wih2, Whh2, bih2, bhh2,
                               out, ws, it, it + 1, 0);
        }
    }
}

// Round 5
// 9040.881 us; speedup vs baseline: 6.9982x; 1.8491x over previous
//
#include <hip/hip_runtime.h>
#include <math.h>

#define TSEQ 500
#define BQ   200
#define DIN  300
#define H1   256
#define H2   300
#define K1   556          // 300+256 == 256+300
#define KP   576          // K padded: 18 MFMA k-steps of 32
#define KCH  72           // 576/8 chunks of 8 bf16 (16B)
#define H1P  264          // h1/o1 row stride (units, padded, 16B-aligned rows)
#define H2P  304          // h2 row stride
#define BP   224          // batch padded to 7*32
#define NBLK 490          // 7 batch-chunks * (32 L1 + 38 L2 gate-tiles)
#define CBLK 70           // blocks per chunk

// ws byte offsets (all 16B aligned)
#define WS_H1  0          // ushort [2][BP][H1P]
#define WS_O1  236544     // ushort [2][BP][H1P]  masked layer1 out
#define WS_H2  473088     // ushort [2][BP][H2P]
#define WS_C1  745472     // float  [256][BP]   (fallback path only)
#define WS_C2  974848     // float  [304][BP]   (fallback path only)
#define WS_BAR 1247232    // 7 chunk barriers: monotonic counter at c*256
#define WS_MSET 1249024
#define H1HALF (BP*H1P)   // 59136 ushorts per buffer half
#define H2HALF (BP*H2P)   // 68096

typedef __attribute__((ext_vector_type(8))) short short8;
typedef __attribute__((ext_vector_type(4))) float f32x4;
typedef unsigned long long u64;

__device__ __forceinline__ float sigf(float v){ return 1.0f/(1.0f+__expf(-v)); }
__device__ __forceinline__ float tanhf_(float v){
    v = fminf(15.0f, fmaxf(-15.0f, v));
    float e = __expf(2.0f*v);
    return (e-1.0f)/(e+1.0f);
}
__device__ __forceinline__ unsigned short f2bf(float f){   // RNE, finite inputs
    unsigned int xx = __builtin_bit_cast(unsigned int, f);
    xx = (xx + 0x7FFFu + ((xx>>16)&1u)) >> 16;
    return (unsigned short)xx;
}
// system-scope (sc0 sc1) load: bypasses L1/L2, serviced at the MALL coherence
// point -> cannot see stale XCD-cached data. Compiler tracks waitcnts.
__device__ __forceinline__ u64 ld_sys(const void* p){
    return __hip_atomic_load((u64*)p, __ATOMIC_RELAXED, __HIP_MEMORY_SCOPE_SYSTEM);
}
// RETURNING atomic swap as the state-publish store: unlike a plain sc0sc1
// store (posted write — vmcnt retires on TCC accept, NOT on MALL arrival),
// a returning atomic's vmcnt retires only after the MALL slice executed it.
// So s_waitcnt vmcnt(0) (inside __syncthreads) => state is globally applied
// BEFORE the barrier-arrival atomic. asm-consume the result so the compiler
// cannot select the non-returning (postable) variant.
__device__ __forceinline__ void st_sys_applied(void* p, u64 v){
    u64 old = __hip_atomic_exchange((u64*)p, v, __ATOMIC_RELAXED,
                                    __HIP_MEMORY_SCOPE_SYSTEM);
    asm volatile("" :: "v"(old));
}

union U16B { short8 s8; u64 u[2]; unsigned short us[8]; };

__global__ __launch_bounds__(256, 2)
void lstm_mfma(const float* __restrict__ x, const int* __restrict__ lengths,
               const float* __restrict__ Wih1, const float* __restrict__ Whh1,
               const float* __restrict__ bih1, const float* __restrict__ bhh1,
               const float* __restrict__ Wih2, const float* __restrict__ Whh2,
               const float* __restrict__ bih2, const float* __restrict__ bhh2,
               float* __restrict__ out, char* __restrict__ wsb,
               int it_begin, int it_end, int coop)
{
    __shared__ unsigned short Wl[32*KP];     // weights, swizzled [row][k] bf16 (persistent)
    __shared__ unsigned short Al[32*KP];     // activations, swizzled [batch][k] bf16
    __shared__ float gl[32*33];              // gate exchange (stride 33)
    __shared__ float bias[32];
    __shared__ unsigned short htr[8*34];     // h transpose buffer (bf16)
    __shared__ unsigned short otr[8*34];     // masked-h transpose buffer (L1)
    __shared__ float ftr[8*33];              // out2 f32 transpose buffer (L2)

    const int tid = threadIdx.x;
    const int bid = blockIdx.x;
    const int mc = bid/70;                   // batch chunk 0..6
    const int local = bid - mc*70;
    const bool l1 = local < 32;
    const int gt = l1 ? local : local - 32;  // gate tile (8 hidden units)
    const int Hl   = l1 ? H1 : H2;
    const int DINl = l1 ? DIN : H1;

    unsigned short* h1s = (unsigned short*)(wsb + WS_H1);
    unsigned short* o1s = (unsigned short*)(wsb + WS_O1);
    unsigned short* h2s = (unsigned short*)(wsb + WS_H2);
    float* c1 = (float*)(wsb + WS_C1);
    float* c2 = (float*)(wsb + WS_C2);
    unsigned* barc = (unsigned*)(wsb + WS_BAR + mc*256);   // monotonic arrival counter

    // ---- stage weights once: row r = 4*u_local + gate, swizzled 16B chunks ----
    {
        const float* Wih = l1 ? Wih1 : Wih2;
        const float* Whh = l1 ? Whh1 : Whh2;
        for (int i = 0; i < 9; ++i){
            int e = tid + i*256;             // 32*72 = 2304 chunks
            int r = e/KCH, kc = e - r*KCH;
            int u = r>>2, g = r&3;
            int unit = gt*8 + u;
            bool vr = unit < Hl;             // L2 tile 37: units 300..303 are pad
            int grow = g*Hl + unit;
            unsigned short v8[8];
            #pragma unroll
            for (int j = 0; j < 8; ++j){
                int k = kc*8 + j;
                float v = 0.0f;
                if (vr && k < K1)
                    v = (k < DINl) ? Wih[(size_t)grow*DINl + k]
                                   : Whh[(size_t)grow*Hl + (k - DINl)];
                v8[j] = f2bf(v);
            }
            *(short8*)&Wl[r*KP + ((kc ^ (r&7))<<3)] = *(short8*)v8;
        }
        if (tid < 32){
            int u = tid>>2, g = tid&3, unit = gt*8 + u;
            bias[tid] = (unit < Hl)
                ? ((l1?bih1:bih2)[g*Hl+unit] + (l1?bhh1:bhh2)[g*Hl+unit]) : 0.0f;
        }
    }

    // MFMA lane mapping: A-frag row = lane&15, k-group = lane>>4; D: row=(l>>4)*4+q, col=l&15
    const int wave = tid>>6, lane = tid&63;
    const int wr = wave>>1, wb = wave&1;     // fragment grid 2x2 of 16x16
    const int fr = lane&15, fg = lane>>4;
    const int sw = fr&7;                     // (wr*16+fr)&7 == fr&7 (wr*16 mult of 8)
    const unsigned short* wrow = &Wl[(wr*16 + fr)*KP];
    const unsigned short* arow = &Al[(wb*16 + fr)*KP];
    const int gm = wr*16 + fg*4, gn = wb*16 + fr;

    // epilogue mapping: (hidden unit local, batch local) — iteration-invariant,
    // so the cell state c lives in a register (block-private, never exchanged)
    const int eu = tid>>5, ebl = tid&31;
    const int bg_e = mc*32 + ebl;
    const int unit_e = gt*8 + eu;
    const int len_r = (l1 && bg_e < BQ) ? lengths[bg_e] : -1;
    float creg = 0.0f;
    if (!coop) creg = (l1 ? c1 : c2)[unit_e*BP + bg_e];   // fallback: resume from ws

    __syncthreads();

    for (int it = it_begin; it < it_end; ++it){
        const bool active = l1 ? (it < TSEQ) : (it >= 1);
        if (active){
            const int t = l1 ? it : it - 1;
            const unsigned short* h1p = h1s + (it&1)*H1HALF;
            const unsigned short* o1p = o1s + ((it-1)&1)*H1HALF;
            const unsigned short* h2p = h2s + ((it-1)&1)*H2HALF;

            // ---- stage full activation panel [32 b][576 k] (bf16, swizzled) ----
            for (int i = 0; i < 9; ++i){
                int e = tid + i*256;
                int bl = e/KCH, kc = e - bl*KCH;
                int bg = mc*32 + bl;
                U16B v;
                if (bg >= BQ || kc >= 70){
                    v.u[0] = 0; v.u[1] = 0;
                } else if (l1){
                    if (kc <= 36){                       // pure x: fp32 -> bf16 (cached loads)
                        const float* xp = x + ((size_t)bg*TSEQ + t)*DIN + kc*8;
                        float4 f0 = *(const float4*)xp;
                        float4 f1 = *(const float4*)(xp + 4);
                        v.us[0]=f2bf(f0.x); v.us[1]=f2bf(f0.y); v.us[2]=f2bf(f0.z); v.us[3]=f2bf(f0.w);
                        v.us[4]=f2bf(f1.x); v.us[5]=f2bf(f1.y); v.us[6]=f2bf(f1.z); v.us[7]=f2bf(f1.w);
                    } else if (kc == 37){                // x 296..299 | h1 units 0..3
                        const float* xp = x + ((size_t)bg*TSEQ + t)*DIN + 296;
                        float4 f0 = *(const float4*)xp;
                        v.us[0]=f2bf(f0.x); v.us[1]=f2bf(f0.y); v.us[2]=f2bf(f0.z); v.us[3]=f2bf(f0.w);
                        v.u[1] = ld_sys(h1p + (size_t)bg*H1P);
                    } else {                             // pure h1 (system-scope, 8B granules)
                        const unsigned short* hp = h1p + (size_t)bg*H1P + (kc*8 - DIN);
                        v.u[0] = ld_sys(hp);
                        v.u[1] = ld_sys(hp + 4);
                    }
                } else {                                 // L2: o1 | h2 (system-scope)
                    const unsigned short* sp = (kc <= 31)
                        ? (o1p + (size_t)bg*H1P + kc*8)
                        : (h2p + (size_t)bg*H2P + (kc*8 - 256)); // kc=69: pad units stay 0
                    v.u[0] = ld_sys(sp);
                    v.u[1] = ld_sys(sp + 4);
                }
                *(short8*)&Al[bl*KP + ((kc ^ (bl&7))<<3)] = v.s8;
            }
            __syncthreads();

            // ---- gates[32r x 32b] = W * A^T via 18 barrier-free MFMA steps ----
            f32x4 acc = {0.f, 0.f, 0.f, 0.f};
            #pragma unroll
            for (int ks = 0; ks < 18; ++ks){
                int off = ((ks*4 + fg) ^ sw) << 3;
                short8 wa = *(const short8*)(wrow + off);
                short8 ab = *(const short8*)(arow + off);
                acc = __builtin_amdgcn_mfma_f32_16x16x32_bf16(wa, ab, acc, 0, 0, 0);
            }
            #pragma unroll
            for (int q = 0; q < 4; ++q) gl[(gm+q)*33 + gn] = acc[q];
            __syncthreads();

            // ---- fp32 cell update (c in register) ----
            {
                float gi = gl[(eu*4+0)*33 + ebl] + bias[eu*4+0];
                float gf = gl[(eu*4+1)*33 + ebl] + bias[eu*4+1];
                float gg = gl[(eu*4+2)*33 + ebl] + bias[eu*4+2];
                float go = gl[(eu*4+3)*33 + ebl] + bias[eu*4+3];
                float iv = sigf(gi), fv = sigf(gf), cv = tanhf_(gg), ov = sigf(go);
                float c = fmaf(fv, creg, iv*cv);
                creg = c;
                float h = ov * tanhf_(c);
                if (l1){
                    float hm = (it < len_r) ? h : 0.0f;   // pad_packed mask
                    htr[eu*34 + ebl] = f2bf(h);
                    otr[eu*34 + ebl] = f2bf(hm);
                    if (it == len_r - 1)
                        out[30000000 + (size_t)bg_e*H1 + unit_e] = h;  // h_value (fp32 h)
                } else {
                    htr[eu*34 + ebl] = (unit_e < H2) ? f2bf(h) : (unsigned short)0;
                    ftr[eu*33 + ebl] = h;
                }
            }
            __syncthreads();

            // ---- packed transposed state publish (returning-swap => applied
            //      at MALL once wave0's vmcnt drains at the next barrier) ----
            if (tid < 32){
                int bgp = mc*32 + tid;
                U16B pv;
                if (l1){
                    #pragma unroll
                    for (int u2 = 0; u2 < 8; ++u2) pv.us[u2] = htr[u2*34 + tid];
                    u64* dp = (u64*)&h1s[((it+1)&1)*H1HALF + (size_t)bgp*H1P + gt*8];
                    st_sys_applied(dp, pv.u[0]); st_sys_applied(dp+1, pv.u[1]);
                    #pragma unroll
                    for (int u2 = 0; u2 < 8; ++u2) pv.us[u2] = otr[u2*34 + tid];
                    u64* op8 = (u64*)&o1s[(it&1)*H1HALF + (size_t)bgp*H1P + gt*8];
                    st_sys_applied(op8, pv.u[0]); st_sys_applied(op8+1, pv.u[1]);
                } else {
                    #pragma unroll
                    for (int u2 = 0; u2 < 8; ++u2) pv.us[u2] = htr[u2*34 + tid];
                    u64* dp = (u64*)&h2s[(it&1)*H2HALF + (size_t)bgp*H2P + gt*8];
                    st_sys_applied(dp, pv.u[0]); st_sys_applied(dp+1, pv.u[1]);
                    if (bgp < BQ){
                        float* op = out + (size_t)bgp*150000 + (size_t)t*300 + gt*8;
                        float4 q0;
                        q0.x = ftr[0*33+tid]; q0.y = ftr[1*33+tid];
                        q0.z = ftr[2*33+tid]; q0.w = ftr[3*33+tid];
                        *(float4*)op = q0;
                        if (gt < 37){   // tile 37 covers units 296..303: only 296..299 valid
                            float4 q1;
                            q1.x = ftr[4*33+tid]; q1.y = ftr[5*33+tid];
                            q1.z = ftr[6*33+tid]; q1.w = ftr[7*33+tid];
                            *(float4*)(op + 4) = q1;
                        }
                    }
                }
            }
        }

        // ---- per-chunk barrier: monotonic system-scope counter. Wave 0 holds
        // both the state swaps and the arrival add; its s_waitcnt vmcnt(0) at
        // __syncthreads guarantees the swaps executed at the MALL before the
        // add is issued. Consumers poll, then read state with sc-bypass loads.
        if (coop && (it + 1 < it_end)){
            __syncthreads();
            if (tid == 0){
                const unsigned tgt = (unsigned)(it - it_begin + 1) * CBLK;
                __hip_atomic_fetch_add(barc, 1u, __ATOMIC_RELAXED,
                                       __HIP_MEMORY_SCOPE_SYSTEM);
                while (__hip_atomic_load(barc, __ATOMIC_RELAXED,
                                         __HIP_MEMORY_SCOPE_SYSTEM) < tgt)
                    __builtin_amdgcn_s_sleep(1);
            }
            __syncthreads();
        }
    }

    if (!coop) (l1 ? c1 : c2)[unit_e*BP + bg_e] = creg;   // fallback: persist c
}

extern "C" void kernel_launch(void* const* d_in, const int* in_sizes, int n_in,
                              void* d_out, int out_size, void* d_ws, size_t ws_size,
                              hipStream_t stream) {
    const float* x    = (const float*)d_in[0];
    const int*   lens = (const int*)  d_in[1];
    const float* Wih1 = (const float*)d_in[2];
    const float* Whh1 = (const float*)d_in[3];
    const float* bih1 = (const float*)d_in[4];
    const float* bhh1 = (const float*)d_in[5];
    const float* Wih2 = (const float*)d_in[6];
    const float* Whh2 = (const float*)d_in[7];
    const float* bih2 = (const float*)d_in[8];
    const float* bhh2 = (const float*)d_in[9];
    float* out = (float*)d_out;
    char*  ws  = (char*)d_ws;

    // zero state buffers + pad regions + barrier counters every call (deterministic)
    hipMemsetAsync(d_ws, 0, (size_t)WS_MSET, stream);

    int ib = 0, ie = TSEQ + 1, coop = 1;
    void* args[] = {(void*)&x, (void*)&lens, (void*)&Wih1, (void*)&Whh1, (void*)&bih1, (void*)&bhh1,
                    (void*)&Wih2, (void*)&Whh2, (void*)&bih2, (void*)&bhh2,
                    (void*)&out, (void*)&ws, (void*)&ib, (void*)&ie, (void*)&coop};
    hipError_t err = hipLaunchCooperativeKernel((const void*)lstm_mfma, dim3(NBLK), dim3(256),
                                                args, 0, stream);
    if (err != hipSuccess) {
        (void)hipGetLastError();   // fall back: one launch per iteration (state in ws)
        for (int it = 0; it <= TSEQ; ++it) {
            hipLaunchKernelGGL(lstm_mfma, dim3(NBLK), dim3(256), 0, stream,
                               x, lens, Wih1, Whh1, bih1, bhh1, Wih2, Whh2, bih2, bhh2,
                               out, ws, it, it + 1, 0);
        }
    }
}

// Round 6
// 3995.100 us; speedup vs baseline: 15.8369x; 2.2630x over previous
//
#include <hip/hip_runtime.h>
#include <math.h>

#define TSEQ 500
#define BQ   200
#define DIN  300
#define H1   256
#define H2   300
#define K1   556          // 300+256 == 256+300
#define KP   576          // 18 MFMA k-steps of 32
#define KCH  72           // 576/8 16B chunks per row
#define H1P  264          // h1 row stride (units, padded)
#define H2P  304          // h2 row stride
#define BP   224          // batch padded to 7*32
#define NCH  7            // batch chunks
#define LB1  8            // L1 blocks per chunk (128 gate rows = 32 units each)
#define LB2  10           // L2 blocks per chunk (1280 rows >= 1216)
#define LBT  18
#define NBLK 126          // 7 * 18, 512 threads each

#define H1SLOT (BP*H1P)   // ushorts per h1 slot (triple-buffered)
#define H2SLOT (BP*H2P)

// ws byte offsets (16B aligned)
#define WS_H1   0         // ushort [3][BP][H1P]  = 354816 B
#define WS_H2   354816    // ushort [3][BP][H2P]  = 408576 B
#define WS_C1   763392    // float  [256][BP]   (fallback only)
#define WS_C2   992768    // float  [320][BP]   (fallback only)
#define WS_FLG  1279488   // 7 chunks * 128 B: 18 int flags each
#define WS_MSET 1280384

typedef __attribute__((ext_vector_type(8))) short short8;
typedef __attribute__((ext_vector_type(4))) float f32x4;
typedef unsigned long long u64;

__device__ __forceinline__ float sigf(float v){ return 1.0f/(1.0f+__expf(-v)); }
__device__ __forceinline__ float tanhf_(float v){
    v = fminf(15.0f, fmaxf(-15.0f, v));
    float e = __expf(2.0f*v);
    return (e-1.0f)/(e+1.0f);
}
__device__ __forceinline__ unsigned short f2bf(float f){   // RNE, finite inputs
    unsigned int xx = __builtin_bit_cast(unsigned int, f);
    xx = (xx + 0x7FFFu + ((xx>>16)&1u)) >> 16;
    return (unsigned short)xx;
}
// system-scope (sc0 sc1) load: bypasses L1/L2, serviced at MALL -> never stale.
__device__ __forceinline__ u64 ld_sys(const void* p){
    return __hip_atomic_load((u64*)p, __ATOMIC_RELAXED, __HIP_MEMORY_SCOPE_SYSTEM);
}
// RETURNING atomic swap as state publish: vmcnt retires only when the MALL
// executed the RMW (a plain sc0sc1 store is posted and can be overtaken by a
// later flag on another line -- round-4 bug). asm-consume the old value so the
// compiler can't pick the non-returning variant. Proven stable in round 5.
__device__ __forceinline__ void st_sys_applied(void* p, u64 v){
    u64 old = __hip_atomic_exchange((u64*)p, v, __ATOMIC_RELAXED,
                                    __HIP_MEMORY_SCOPE_SYSTEM);
    asm volatile("" :: "v"(old));
}

union U16B { short8 s8; u64 u[2]; unsigned short us[8]; };
union U8B  { u64 u; unsigned short us[4]; };

__global__ __launch_bounds__(512, 2)
void lstm_mfma(const float* __restrict__ x, const int* __restrict__ lengths,
               const float* __restrict__ Wih1, const float* __restrict__ Whh1,
               const float* __restrict__ bih1, const float* __restrict__ bhh1,
               const float* __restrict__ Wih2, const float* __restrict__ Whh2,
               const float* __restrict__ bih2, const float* __restrict__ bhh2,
               float* __restrict__ out, char* __restrict__ wsb,
               int it_begin, int it_end, int coop)
{
    // LDS: 36864 (A) + 16896 (gates) + 512 (bias) + 2112 (htr) + 4224 (ftr) + 128 = 60736 B
    __shared__ unsigned short Al[32*KP];   // activation panel [32 b][576 k], swizzled
    __shared__ float gl[128*33];           // gate exchange
    __shared__ float bias[128];
    __shared__ unsigned short htr[32*33];  // h transpose (bf16, unmasked)
    __shared__ float ftr[32*33];           // out2 f32 transpose (L2)
    __shared__ int lenl[32];               // chunk batch lengths (L2 masking)

    const int tid = threadIdx.x;
    const int bid = blockIdx.x;
    const int mc = bid / LBT;              // batch chunk 0..6
    const int lb = bid - mc*LBT;           // 0..7 = L1 blocks, 8..17 = L2 blocks
    const bool l1 = (lb < LB1);
    const int ub = (l1 ? lb : lb - LB1) * 32;   // unit base (32 units per block)
    const int Hl = l1 ? H1 : H2;
    const int DINl = l1 ? DIN : H1;

    unsigned short* h1s = (unsigned short*)(wsb + WS_H1);
    unsigned short* h2s = (unsigned short*)(wsb + WS_H2);
    float* c1 = (float*)(wsb + WS_C1);
    float* c2 = (float*)(wsb + WS_C2);
    int* flg = (int*)(wsb + WS_FLG + mc*128);

    const int wave = tid >> 6, lane = tid & 63;
    const int fr = lane & 15, fg = lane >> 4;
    const int sw = fr & 7;

    // ---- weights -> VGPR, once (row = wave*16+fr, gate-interleaved r=4u+g) ----
    short8 wreg[18];
    {
        const int row = wave*16 + fr;
        const int u = row >> 2, g = row & 3;
        const int unit = ub + u;
        const bool vr = unit < Hl;                    // pad rows (L2 last block)
        const float* Wih = l1 ? Wih1 : Wih2;
        const float* Whh = l1 ? Whh1 : Whh2;
        const long grow = (long)g*Hl + unit;
        #pragma unroll
        for (int ks = 0; ks < 18; ++ks){
            unsigned short v8[8];
            #pragma unroll
            for (int j = 0; j < 8; ++j){
                int k = ks*32 + fg*8 + j;
                float v = 0.0f;
                if (vr && k < K1)
                    v = (k < DINl) ? Wih[grow*DINl + k] : Whh[grow*Hl + (k - DINl)];
                v8[j] = f2bf(v);
            }
            wreg[ks] = *(short8*)v8;
        }
    }
    if (tid < 128){
        int u = tid >> 2, g = tid & 3, unit = ub + u;
        bias[tid] = (unit < Hl)
            ? ((l1?bih1:bih2)[g*Hl+unit] + (l1?bhh1:bhh2)[g*Hl+unit]) : 0.0f;
    }
    if (tid < 32) lenl[tid] = (mc*32 + tid < BQ) ? lengths[mc*32 + tid] : 0;

    const unsigned short* arow0 = &Al[fr*KP];
    const unsigned short* arow1 = &Al[(16 + fr)*KP];

    // epilogue mapping: thread -> 2 cells (units eu, eu+16) x batch ebl
    const int eu = tid >> 5, ebl = tid & 31;
    const int bg_e = mc*32 + ebl;
    const int unit0 = ub + eu, unit1 = ub + eu + 16;
    const int len_r = (l1 && bg_e < BQ) ? lengths[bg_e] : -1;
    float creg0 = 0.0f, creg1 = 0.0f;
    if (!coop){
        float* cs = l1 ? c1 : c2;
        creg0 = cs[unit0*BP + bg_e];
        creg1 = cs[unit1*BP + bg_e];
    }

    __syncthreads();

    for (int it = it_begin; it < it_end; ++it){
        const bool active = l1 ? (it < TSEQ) : (it >= 1);
        const int t = l1 ? it : it - 1;

        // ---- pre-stage x (flag-independent; overlaps producer latency) ----
        if (active && l1){
            for (int i = 0; i < 5; ++i){
                int e = tid + i*512;
                if (e >= 32*KCH) break;
                int bl = e/KCH, kc = e - bl*KCH;
                int bg = mc*32 + bl;
                if (kc <= 36 && bg < BQ){
                    const float* xp = x + ((size_t)bg*TSEQ + t)*DIN + kc*8;
                    float4 f0 = *(const float4*)xp;
                    float4 f1 = *(const float4*)(xp + 4);
                    U16B v;
                    v.us[0]=f2bf(f0.x); v.us[1]=f2bf(f0.y); v.us[2]=f2bf(f0.z); v.us[3]=f2bf(f0.w);
                    v.us[4]=f2bf(f1.x); v.us[5]=f2bf(f1.y); v.us[6]=f2bf(f1.z); v.us[7]=f2bf(f1.w);
                    *(short8*)&Al[bl*KP + ((kc ^ (bl&7))<<3)] = v.s8;
                }
            }
        }

        // ---- wait producer flags: one wave-instruction polls all 18 flags.
        // L1 needs: L1 flags >= it (h1 data), L2 flags >= it-1 (WAR slack from
        // triple buffering). L2 needs: all >= it.
        if (coop && it > it_begin){
            if (tid < LBT){
                int target = (tid < LB1) ? it : (l1 ? it - 1 : it);
                if (target > 0)
                    while (__hip_atomic_load(&flg[tid], __ATOMIC_RELAXED,
                                             __HIP_MEMORY_SCOPE_SYSTEM) < target)
                        __builtin_amdgcn_s_sleep(1);
            }
            __syncthreads();
        }

        // ---- stage recurrent parts (system-scope; L2 masks h1 -> "o1") ----
        if (active){
            const unsigned short* h1p = h1s + (it % 3)*H1SLOT;       // h(t=it-1)
            const unsigned short* h2p = h2s + ((it + 2) % 3)*H2SLOT; // h2(t=it-1)
            for (int i = 0; i < 5; ++i){
                int e = tid + i*512;
                if (e >= 32*KCH) break;
                int bl = e/KCH, kc = e - bl*KCH;
                int bg = mc*32 + bl;
                if (l1 && kc <= 36 && bg < BQ) continue;   // pre-staged x
                U16B v;
                if (bg >= BQ || kc >= 70){
                    v.u[0] = 0; v.u[1] = 0;
                } else if (l1){
                    if (kc == 37){                         // x 296..299 | h1 units 0..3
                        const float* xp = x + ((size_t)bg*TSEQ + t)*DIN + 296;
                        float4 f0 = *(const float4*)xp;
                        v.us[0]=f2bf(f0.x); v.us[1]=f2bf(f0.y); v.us[2]=f2bf(f0.z); v.us[3]=f2bf(f0.w);
                        v.u[1] = ld_sys(h1p + (size_t)bg*H1P);
                    } else {                               // pure h1 (unmasked recurrence)
                        const unsigned short* hp = h1p + (size_t)bg*H1P + (kc*8 - DIN);
                        v.u[0] = ld_sys(hp);
                        v.u[1] = ld_sys(hp + 4);
                    }
                } else {
                    if (kc <= 31){                         // masked h1 == packed "o1"
                        if (t < lenl[bl]){
                            const unsigned short* hp = h1p + (size_t)bg*H1P + kc*8;
                            v.u[0] = ld_sys(hp); v.u[1] = ld_sys(hp + 4);
                        } else { v.u[0] = 0; v.u[1] = 0; }
                    } else {                               // h2 (kc=69 reads zero pad 300..303)
                        const unsigned short* hp = h2p + (size_t)bg*H2P + (kc*8 - 256);
                        v.u[0] = ld_sys(hp); v.u[1] = ld_sys(hp + 4);
                    }
                }
                *(short8*)&Al[bl*KP + ((kc ^ (bl&7))<<3)] = v.s8;
            }
        }
        __syncthreads();

        // ---- 36 MFMA, weights from VGPR (no LDS weight reads) ----
        if (active){
            f32x4 acc0 = {0.f,0.f,0.f,0.f}, acc1 = {0.f,0.f,0.f,0.f};
            #pragma unroll
            for (int ks = 0; ks < 18; ++ks){
                const int off = ((ks*4 + fg) ^ sw) << 3;
                short8 b0 = *(const short8*)(arow0 + off);
                short8 b1 = *(const short8*)(arow1 + off);
                acc0 = __builtin_amdgcn_mfma_f32_16x16x32_bf16(wreg[ks], b0, acc0, 0, 0, 0);
                acc1 = __builtin_amdgcn_mfma_f32_16x16x32_bf16(wreg[ks], b1, acc1, 0, 0, 0);
            }
            const int gr = wave*16 + fg*4;
            #pragma unroll
            for (int q = 0; q < 4; ++q){
                gl[(gr+q)*33 + fr]      = acc0[q];
                gl[(gr+q)*33 + 16 + fr] = acc1[q];
            }
        }
        __syncthreads();

        // ---- fp32 cell update, 2 cells/thread, c in registers ----
        if (active){
            {
                float gi = gl[(eu*4+0)*33 + ebl] + bias[eu*4+0];
                float gf = gl[(eu*4+1)*33 + ebl] + bias[eu*4+1];
                float gg = gl[(eu*4+2)*33 + ebl] + bias[eu*4+2];
                float go = gl[(eu*4+3)*33 + ebl] + bias[eu*4+3];
                float iv = sigf(gi), fv = sigf(gf), cv = tanhf_(gg), ov = sigf(go);
                float c = fmaf(fv, creg0, iv*cv); creg0 = c;
                float h = ov * tanhf_(c);
                if (l1){
                    htr[eu*33 + ebl] = f2bf(h);           // UNMASKED (recurrence)
                    if (it == len_r - 1) out[30000000 + (size_t)bg_e*H1 + unit0] = h;
                } else {
                    htr[eu*33 + ebl] = (unit0 < H2) ? f2bf(h) : (unsigned short)0;
                    ftr[eu*33 + ebl] = h;
                }
            }
            {
                const int ul = eu + 16;
                float gi = gl[(ul*4+0)*33 + ebl] + bias[ul*4+0];
                float gf = gl[(ul*4+1)*33 + ebl] + bias[ul*4+1];
                float gg = gl[(ul*4+2)*33 + ebl] + bias[ul*4+2];
                float go = gl[(ul*4+3)*33 + ebl] + bias[ul*4+3];
                float iv = sigf(gi), fv = sigf(gf), cv = tanhf_(gg), ov = sigf(go);
                float c = fmaf(fv, creg1, iv*cv); creg1 = c;
                float h = ov * tanhf_(c);
                if (l1){
                    htr[ul*33 + ebl] = f2bf(h);
                    if (it == len_r - 1) out[30000000 + (size_t)bg_e*H1 + unit1] = h;
                } else {
                    htr[ul*33 + ebl] = (unit1 < H2) ? f2bf(h) : (unsigned short)0;
                    ftr[ul*33 + ebl] = h;
                }
            }
        }
        __syncthreads();

        // ---- publish (returning swaps) + out2 stores ----
        if (active && tid < 256){
            const int b = tid >> 3, ch = tid & 7;        // batch local, 4-unit chunk
            const int bgp = mc*32 + b;
            U8B pv;
            #pragma unroll
            for (int i2 = 0; i2 < 4; ++i2) pv.us[i2] = htr[(ch*4 + i2)*33 + b];
            if (l1){
                st_sys_applied(&h1s[((it+1)%3)*H1SLOT + (size_t)bgp*H1P + ub + ch*4], pv.u);
            } else {
                const int unit4 = ub + ch*4;
                if (unit4 < H2P)                          // skip pad units 304..319
                    st_sys_applied(&h2s[(it%3)*H2SLOT + (size_t)bgp*H2P + unit4], pv.u);
                if (bgp < BQ && unit4 < H2){
                    float4 q0;
                    q0.x = ftr[(ch*4+0)*33 + b];
                    q0.y = ftr[(ch*4+1)*33 + b];
                    q0.z = ftr[(ch*4+2)*33 + b];
                    q0.w = ftr[(ch*4+3)*33 + b];
                    *(float4*)(out + (size_t)bgp*150000 + (size_t)t*300 + unit4) = q0;
                }
            }
        }
        // ---- flag release: barrier drains vmcnt (swaps applied at MALL),
        //      then the posted flag store cannot lead the state. ----
        if (coop){
            __syncthreads();
            if (tid == 0)
                __hip_atomic_store(&flg[lb], it + 1, __ATOMIC_RELAXED,
                                   __HIP_MEMORY_SCOPE_SYSTEM);
        }
    }

    if (!coop){
        float* cs = l1 ? c1 : c2;
        cs[unit0*BP + bg_e] = creg0;
        cs[unit1*BP + bg_e] = creg1;
    }
}

extern "C" void kernel_launch(void* const* d_in, const int* in_sizes, int n_in,
                              void* d_out, int out_size, void* d_ws, size_t ws_size,
                              hipStream_t stream) {
    const float* x    = (const float*)d_in[0];
    const int*   lens = (const int*)  d_in[1];
    const float* Wih1 = (const float*)d_in[2];
    const float* Whh1 = (const float*)d_in[3];
    const float* bih1 = (const float*)d_in[4];
    const float* bhh1 = (const float*)d_in[5];
    const float* Wih2 = (const float*)d_in[6];
    const float* Whh2 = (const float*)d_in[7];
    const float* bih2 = (const float*)d_in[8];
    const float* bhh2 = (const float*)d_in[9];
    float* out = (float*)d_out;
    char*  ws  = (char*)d_ws;

    // zero state slots + pads + flags + fallback c every call (deterministic)
    hipMemsetAsync(d_ws, 0, (size_t)WS_MSET, stream);

    int ib = 0, ie = TSEQ + 1, coop = 1;
    void* args[] = {(void*)&x, (void*)&lens, (void*)&Wih1, (void*)&Whh1, (void*)&bih1, (void*)&bhh1,
                    (void*)&Wih2, (void*)&Whh2, (void*)&bih2, (void*)&bhh2,
                    (void*)&out, (void*)&ws, (void*)&ib, (void*)&ie, (void*)&coop};
    hipError_t err = hipLaunchCooperativeKernel((const void*)lstm_mfma, dim3(NBLK), dim3(512),
                                                args, 0, stream);
    if (err != hipSuccess) {
        (void)hipGetLastError();   // fall back: one launch per iteration (state in ws)
        for (int it = 0; it <= TSEQ; ++it) {
            hipLaunchKernelGGL(lstm_mfma, dim3(NBLK), dim3(512), 0, stream,
                               x, lens, Wih1, Whh1, bih1, bhh1, Wih2, Whh2, bih2, bhh2,
                               out, ws, it, it + 1, 0);
        }
    }
}

// Round 9
// 2562.854 us; speedup vs baseline: 24.6874x; 1.5588x over previous
//
#include <hip/hip_runtime.h>
#include <math.h>

#define TSEQ 500
#define BQ   200
#define DIN  300
#define H1   256
#define H2   300
#define K1   556          // both layers: 256 recurrent/o1 + 300 x/h2
#define KP   576          // 18 MFMA k-steps of 32; k 0..255 = state, 256..555 = x|h2
#define H1P  256          // h1 row stride (ushorts)
#define H2P  304          // h2 row stride (300 + 4 zero pad)
#define BQC  25           // batches per chunk (8 chunks * 25 = 200)
#define LB1  8            // L1 blocks per chunk (32 units each)
#define LBT  18           // blocks per chunk (8 L1 + 10 L2)
#define NBLK 144          // 8 chunks * 18

#define H1SLOT (BQ*H1P)   // 51200 ushorts per slot (triple-buffered)
#define H2SLOT (BQ*H2P)   // 60800

// ws byte offsets (16B aligned)
#define WS_H1   0         // ushort [3][200][256] = 307200 B
#define WS_H2   307200    // ushort [3][200][304] = 364800 B
#define WS_C1   672000    // float [256][200] (fallback path only)
#define WS_C2   876800    // float [320][200] (fallback path only)
#define WS_FLG  1132800   // 8 chunks * 128 B (18 int flags)
#define WS_MSET 1133824

typedef __attribute__((ext_vector_type(8))) short short8;
typedef __attribute__((ext_vector_type(4))) float f32x4;
typedef unsigned long long u64;

__device__ __forceinline__ float sigf(float v){ return 1.0f/(1.0f+__expf(-v)); }
__device__ __forceinline__ float tanhf_(float v){
    v = fminf(15.0f, fmaxf(-15.0f, v));
    float e = __expf(2.0f*v);
    return (e-1.0f)/(e+1.0f);
}
__device__ __forceinline__ unsigned short f2bf(float f){   // RNE, finite inputs
    unsigned int xx = __builtin_bit_cast(unsigned int, f);
    xx = (xx + 0x7FFFu + ((xx>>16)&1u)) >> 16;
    return (unsigned short)xx;
}
// SYSTEM scope (sc0 sc1): bypass L1/L2, serviced at the MALL coherence point.
// Proven stable (rounds 5-6). NO cache flushes anywhere.
__device__ __forceinline__ u64 ld8_sys(const void* p){
    return __hip_atomic_load((const u64*)p, __ATOMIC_RELAXED, __HIP_MEMORY_SCOPE_SYSTEM);
}
// RETURNING swap as state publish: vmcnt retires only when the MALL executed
// the RMW (plain sc0sc1 stores are posted and can be overtaken by the flag on
// another line -- the round-4 race). asm-consume forces the returning variant.
__device__ __forceinline__ void pub8(u64* p, u64 v){
    u64 old = __hip_atomic_exchange(p, v, __ATOMIC_RELAXED, __HIP_MEMORY_SCOPE_SYSTEM);
    asm volatile("" :: "v"(old));
}

union U16B { short8 s8; u64 u[2]; unsigned short us[8]; };
union U8B  { u64 u; unsigned short us[4]; };

__global__ __launch_bounds__(512, 2)
void lstm_mfma(const float* __restrict__ x, const int* __restrict__ lengths,
               const float* __restrict__ Wih1, const float* __restrict__ Whh1,
               const float* __restrict__ bih1, const float* __restrict__ bhh1,
               const float* __restrict__ Wih2, const float* __restrict__ Whh2,
               const float* __restrict__ bih2, const float* __restrict__ bhh2,
               float* __restrict__ out, char* __restrict__ wsb,
               int it_begin, int it_end, int coop)
{
    __shared__ unsigned short Al[32*KP];   // 36864 B  [batch][k] bf16, swizzled
    __shared__ float gl[128*33];           // 16896 B  gate exchange (wave-local)
    __shared__ float bias[128];
    __shared__ int lenl[32];

    const int tid = threadIdx.x;
    const int bid = blockIdx.x;
    const int mc  = bid & 7;               // batch chunk
    const int lbi = bid >> 3;              // 0..17 within chunk
    const bool l1 = lbi < LB1;
    const int ub  = (l1 ? lbi : lbi - LB1) * 32;   // unit base
    const int Hl  = l1 ? H1 : H2;

    unsigned short* h1s = (unsigned short*)(wsb + WS_H1);
    unsigned short* h2s = (unsigned short*)(wsb + WS_H2);
    float* c1 = (float*)(wsb + WS_C1);
    float* c2 = (float*)(wsb + WS_C2);
    int* flg = (int*)(wsb + WS_FLG + mc*128);

    const int wave = tid >> 6, lane = tid & 63;
    const int fr = lane & 15, fg = lane >> 4;
    const int sw = fr & 7;

    // ---- weights -> VGPR, once. Row r = wave*16+fr = 4*u_local + gate.
    //      NEW k layout: k<256 = recurrent/o1 part, k in [256,556) = x/h2 part.
    short8 wreg[18];
    {
        const int row = wave*16 + fr;
        const int u = row >> 2, g = row & 3;
        const int unit = ub + u;
        const bool vr = unit < Hl;                 // L2 block 9 pad units
        const long grow = (long)g*Hl + unit;
        #pragma unroll
        for (int ks = 0; ks < 18; ++ks){
            unsigned short v8[8];
            #pragma unroll
            for (int j = 0; j < 8; ++j){
                int k = ks*32 + fg*8 + j;
                float v = 0.0f;
                if (vr && k < K1){
                    if (l1) v = (k < H1) ? Whh1[grow*H1 + k] : Wih1[grow*DIN + (k - H1)];
                    else    v = (k < H1) ? Wih2[grow*H1 + k] : Whh2[grow*H2 + (k - H1)];
                }
                v8[j] = f2bf(v);
            }
            wreg[ks] = *(short8*)v8;
        }
    }
    if (tid < 128){
        int u = tid >> 2, g = tid & 3, unit = ub + u;
        bias[tid] = (unit < Hl)
            ? ((l1?bih1:bih2)[g*Hl+unit] + (l1?bhh1:bhh2)[g*Hl+unit]) : 0.0f;
    }
    if (tid < 32) lenl[tid] = (tid < BQC) ? lengths[mc*BQC + tid] : 0;

    const unsigned short* arow0 = &Al[fr*KP];
    const unsigned short* arow1 = &Al[(16+fr)*KP];
    const int bg_e = mc*BQC + lane;        // epilogue batch (lane<BQC valid)

    float creg[4] = {0.f, 0.f, 0.f, 0.f};
    if (!coop && lane < 32){
        float* cs = l1 ? c1 : c2;
        #pragma unroll
        for (int i2 = 0; i2 < 4; ++i2) creg[i2] = cs[(ub + wave*4 + i2)*BQ + bg_e];
    }

    __syncthreads();

    for (int it = it_begin; it < it_end; ++it){
        const bool active = l1 ? (it < TSEQ) : (it >= 1);
        const int t = l1 ? it : it - 1;

        // ---- L1: stage x panel (k 256..575) BEFORE the flag wait ----
        if (active && l1){
            #pragma unroll
            for (int i = 0; i < 3; ++i){
                int e = tid + i*512;
                if (e < 1280){
                    int bl = e/40, kcx = 32 + e - (e/40)*40;     // kcx 32..71
                    U16B v; v.u[0] = 0; v.u[1] = 0;
                    if (bl < BQC && kcx <= 69){
                        int bg = mc*BQC + bl;
                        const float* xp = x + ((size_t)bg*TSEQ + t)*DIN + (kcx*8 - 256);
                        float4 f0 = *(const float4*)xp;
                        v.us[0]=f2bf(f0.x); v.us[1]=f2bf(f0.y); v.us[2]=f2bf(f0.z); v.us[3]=f2bf(f0.w);
                        if (kcx <= 68){
                            float4 f1 = *(const float4*)(xp + 4);
                            v.us[4]=f2bf(f1.x); v.us[5]=f2bf(f1.y); v.us[6]=f2bf(f1.z); v.us[7]=f2bf(f1.w);
                        }
                    }
                    *(short8*)&Al[bl*KP + ((kcx ^ (bl&7))<<3)] = v.s8;
                }
            }
        }

        // ---- wait producer flags (SYSTEM -- unconditionally coherent) ----
        // L1 needs L1 flags>=it (data) and L2 flags>=it-1 (WAR, triple buffer);
        // L2 needs all>=it. Flag j==v means block j finished iteration v-1.
        if (coop && it > it_begin && tid < LBT){
            int tgt = l1 ? (tid < LB1 ? it : it - 1) : it;
            if (tgt > 0)
                while (__hip_atomic_load(&flg[tid], __ATOMIC_RELAXED,
                                         __HIP_MEMORY_SCOPE_SYSTEM) < tgt)
                    __builtin_amdgcn_s_sleep(1);
        }
        __syncthreads();   // B0: flags confirmed + x panel staged

        if (active){
            const unsigned short* h1p = h1s + (it % 3)*H1SLOT;       // h1(it-1)
            const unsigned short* h2p = h2s + ((it + 2) % 3)*H2SLOT; // h2(it-1)

            f32x4 acc0 = {0.f,0.f,0.f,0.f}, acc1 = {0.f,0.f,0.f,0.f};

            if (l1){
                // issue h1 state loads (MALL RTT)...
                u64 hv0, hv1, hv2, hv3;
                const int e0 = tid, e1 = tid + 512;
                const int bl0 = e0 >> 5, kc0 = e0 & 31;
                const int bl1 = e1 >> 5, kc1 = e1 & 31;
                if (bl0 < BQC){
                    const unsigned short* hp = h1p + (size_t)(mc*BQC + bl0)*H1P + kc0*8;
                    hv0 = ld8_sys(hp); hv1 = ld8_sys(hp + 4);
                } else { hv0 = 0; hv1 = 0; }
                if (bl1 < BQC){
                    const unsigned short* hp = h1p + (size_t)(mc*BQC + bl1)*H1P + kc1*8;
                    hv2 = ld8_sys(hp); hv3 = ld8_sys(hp + 4);
                } else { hv2 = 0; hv3 = 0; }
                // ...and hide their latency under the x-part MFMA (k-steps 8..17)
                #pragma unroll
                for (int ks = 8; ks < 18; ++ks){
                    const int off = ((ks*4 + fg) ^ sw) << 3;
                    short8 b0 = *(const short8*)(arow0 + off);
                    short8 b1 = *(const short8*)(arow1 + off);
                    acc0 = __builtin_amdgcn_mfma_f32_16x16x32_bf16(wreg[ks], b0, acc0, 0, 0, 0);
                    acc1 = __builtin_amdgcn_mfma_f32_16x16x32_bf16(wreg[ks], b1, acc1, 0, 0, 0);
                }
                U16B w0; w0.u[0] = hv0; w0.u[1] = hv1;
                U16B w1; w1.u[0] = hv2; w1.u[1] = hv3;
                *(short8*)&Al[bl0*KP + ((kc0 ^ (bl0&7))<<3)] = w0.s8;
                *(short8*)&Al[bl1*KP + ((kc1 ^ (bl1&7))<<3)] = w1.s8;
            } else {
                // L2: gather o1 (masked h1) + h2 into regs, then LDS-write
                u64 sv[10];
                #pragma unroll
                for (int i = 0; i < 5; ++i){
                    int e = tid + i*512;
                    u64 a = 0, b = 0;
                    if (e < 2304){
                        int bl = e/72, kc = e - (e/72)*72;
                        if (bl < BQC && kc < 70){
                            int bg = mc*BQC + bl;
                            if (kc < 32){                    // o1 = masked h1
                                if (t < lenl[bl]){
                                    const unsigned short* hp = h1p + (size_t)bg*H1P + kc*8;
                                    a = ld8_sys(hp); b = ld8_sys(hp + 4);
                                }
                            } else {                         // h2 (kc=69 hits zero pad)
                                const unsigned short* hp = h2p + (size_t)bg*H2P + (kc*8 - 256);
                                a = ld8_sys(hp); b = ld8_sys(hp + 4);
                            }
                        }
                    }
                    sv[2*i] = a; sv[2*i+1] = b;
                }
                #pragma unroll
                for (int i = 0; i < 5; ++i){
                    int e = tid + i*512;
                    if (e < 2304){
                        int bl = e/72, kc = e - (e/72)*72;
                        U16B v; v.u[0] = sv[2*i]; v.u[1] = sv[2*i+1];
                        *(short8*)&Al[bl*KP + ((kc ^ (bl&7))<<3)] = v.s8;
                    }
                }
            }
            __syncthreads();   // B1: state panel staged

            // ---- remaining MFMA (L1: k-steps 0..7; L2: all 18) ----
            if (l1){
                #pragma unroll
                for (int ks = 0; ks < 8; ++ks){
                    const int off = ((ks*4 + fg) ^ sw) << 3;
                    short8 b0 = *(const short8*)(arow0 + off);
                    short8 b1 = *(const short8*)(arow1 + off);
                    acc0 = __builtin_amdgcn_mfma_f32_16x16x32_bf16(wreg[ks], b0, acc0, 0, 0, 0);
                    acc1 = __builtin_amdgcn_mfma_f32_16x16x32_bf16(wreg[ks], b1, acc1, 0, 0, 0);
                }
            } else {
                #pragma unroll
                for (int ks = 0; ks < 18; ++ks){
                    const int off = ((ks*4 + fg) ^ sw) << 3;
                    short8 b0 = *(const short8*)(arow0 + off);
                    short8 b1 = *(const short8*)(arow1 + off);
                    acc0 = __builtin_amdgcn_mfma_f32_16x16x32_bf16(wreg[ks], b0, acc0, 0, 0, 0);
                    acc1 = __builtin_amdgcn_mfma_f32_16x16x32_bf16(wreg[ks], b1, acc1, 0, 0, 0);
                }
            }

            // wave-local gate exchange: wave w owns rows 16w..16w+15 entirely;
            // same-wave LDS ops are processed in order -> no barrier needed.
            const int gr = wave*16 + fg*4;
            #pragma unroll
            for (int q = 0; q < 4; ++q){
                gl[(gr+q)*33 + fr]      = acc0[q];
                gl[(gr+q)*33 + 16 + fr] = acc1[q];
            }

            // ---- epilogue: lane b -> units ub+4*wave+0..3, batch b ----
            if (lane < 32){
                float hv[4]; unsigned short hb[4];
                #pragma unroll
                for (int i2 = 0; i2 < 4; ++i2){
                    const int r = wave*16 + i2*4;
                    float gi = gl[(r+0)*33 + lane] + bias[r+0];
                    float gf = gl[(r+1)*33 + lane] + bias[r+1];
                    float gg = gl[(r+2)*33 + lane] + bias[r+2];
                    float go = gl[(r+3)*33 + lane] + bias[r+3];
                    float iv = sigf(gi), fv = sigf(gf), cv = tanhf_(gg), ov = sigf(go);
                    float c = fmaf(fv, creg[i2], iv*cv); creg[i2] = c;
                    hv[i2] = ov * tanhf_(c);
                    hb[i2] = f2bf(hv[i2]);
                }
                const int unit4 = ub + wave*4;
                if (lane < BQC){
                    U8B pv; pv.us[0]=hb[0]; pv.us[1]=hb[1]; pv.us[2]=hb[2]; pv.us[3]=hb[3];
                    if (l1){
                        pub8((u64*)&h1s[((it+1)%3)*H1SLOT + (size_t)bg_e*H1P + unit4], pv.u);
                        if (it == lenl[lane] - 1){           // h_value (fp32 h)
                            float4 q; q.x=hv[0]; q.y=hv[1]; q.z=hv[2]; q.w=hv[3];
                            *(float4*)(out + 30000000 + (size_t)bg_e*H1 + unit4) = q;
                        }
                    } else if (unit4 < H2){
                        pub8((u64*)&h2s[(it%3)*H2SLOT + (size_t)bg_e*H2P + unit4], pv.u);
                        float4 q; q.x=hv[0]; q.y=hv[1]; q.z=hv[2]; q.w=hv[3];
                        *(float4*)(out + (size_t)bg_e*150000 + (size_t)t*300 + unit4) = q;
                    }
                }
            }
        } else {
            __syncthreads();   // B1 (inactive blocks keep barrier count aligned)
        }

        __syncthreads();       // B2: drains all waves' swaps (applied at MALL)
        if (coop && tid == 0)
            __hip_atomic_store(&flg[lbi], it + 1, __ATOMIC_RELAXED,
                               __HIP_MEMORY_SCOPE_SYSTEM);
    }

    if (!coop && lane < 32){
        float* cs = l1 ? c1 : c2;
        #pragma unroll
        for (int i2 = 0; i2 < 4; ++i2) cs[(ub + wave*4 + i2)*BQ + bg_e] = creg[i2];
    }
}

extern "C" void kernel_launch(void* const* d_in, const int* in_sizes, int n_in,
                              void* d_out, int out_size, void* d_ws, size_t ws_size,
                              hipStream_t stream) {
    const float* x    = (const float*)d_in[0];
    const int*   lens = (const int*)  d_in[1];
    const float* Wih1 = (const float*)d_in[2];
    const float* Whh1 = (const float*)d_in[3];
    const float* bih1 = (const float*)d_in[4];
    const float* bhh1 = (const float*)d_in[5];
    const float* Wih2 = (const float*)d_in[6];
    const float* Whh2 = (const float*)d_in[7];
    const float* bih2 = (const float*)d_in[8];
    const float* bhh2 = (const float*)d_in[9];
    float* out = (float*)d_out;
    char*  ws  = (char*)d_ws;

    // zero state slots (incl. pad), flags, fallback c -- every call (deterministic)
    hipMemsetAsync(d_ws, 0, (size_t)WS_MSET, stream);

    int ib = 0, ie = TSEQ + 1, coop = 1;
    void* args[] = {(void*)&x, (void*)&lens, (void*)&Wih1, (void*)&Whh1, (void*)&bih1, (void*)&bhh1,
                    (void*)&Wih2, (void*)&Whh2, (void*)&bih2, (void*)&bhh2,
                    (void*)&out, (void*)&ws, (void*)&ib, (void*)&ie, (void*)&coop};
    hipError_t err = hipLaunchCooperativeKernel((const void*)lstm_mfma, dim3(NBLK), dim3(512),
                                                args, 0, stream);
    if (err != hipSuccess) {
        (void)hipGetLastError();   // fall back: one launch per iteration (state in ws)
        for (int it = 0; it <= TSEQ; ++it) {
            hipLaunchKernelGGL(lstm_mfma, dim3(NBLK), dim3(512), 0, stream,
                               x, lens, Wih1, Whh1, bih1, bhh1, Wih2, Whh2, bih2, bhh2,
                               out, ws, it, it + 1, 0);
        }
    }
}